// Round 8
// baseline (1133.331 us; speedup 1.0000x reference)
//
#include <hip/hip_runtime.h>
#include <hip/hip_bf16.h>
#include <stdint.h>

#define Bn 64
#define Ln 2048
#define Hn 128
#define Vn 32000
#define THn 256            // 2*H
#define LAMBDA_ (1.0f/2048.0f)
#define CC 32              // scan chunk size
#define NCH (Ln/CC)        // 64 chunks
#define KP  132            // p2 kn_p row stride (uints)
#define VS  132            // p2 vp0L/adL row stride (floats)
#define GS  36             // p2 Gt row stride
#define MSR 36             // p2 m_scratch row stride (uints)
#define MSW 576            // p2 m_scratch per-wave size (16*36)
#define HS  132            // p1 h_p/u_p row stride (uints)

typedef short bf16x8 __attribute__((ext_vector_type(8)));
typedef float f32x4  __attribute__((ext_vector_type(4)));

__device__ __forceinline__ float rdlane(float v, int s) {
  return __int_as_float(__builtin_amdgcn_readlane(__float_as_int(v), s));
}

// pack fp32 -> (bf16 hi in low16, bf16 lo in high16), truncation split
__device__ __forceinline__ uint32_t packhl(float x) {
  uint32_t bx = __float_as_uint(x);
  float hf = __uint_as_float(bx & 0xFFFF0000u);
  uint32_t bl = __float_as_uint(x - hf);
  return (bx >> 16) | (bl & 0xFFFF0000u);
}
__device__ __forceinline__ float unpackhl(uint32_t u) {
  return __uint_as_float(u << 16) + __uint_as_float(u & 0xFFFF0000u);
}

struct FragHL { bf16x8 h; bf16x8 l; };
__device__ __forceinline__ FragHL mkfrag(const uint32_t* u) {
  union { uint32_t a[4]; bf16x8 v; } H, L;
  H.a[0] = __builtin_amdgcn_perm(u[1], u[0], 0x05040100u);
  H.a[1] = __builtin_amdgcn_perm(u[3], u[2], 0x05040100u);
  H.a[2] = __builtin_amdgcn_perm(u[5], u[4], 0x05040100u);
  H.a[3] = __builtin_amdgcn_perm(u[7], u[6], 0x05040100u);
  L.a[0] = __builtin_amdgcn_perm(u[1], u[0], 0x07060302u);
  L.a[1] = __builtin_amdgcn_perm(u[3], u[2], 0x07060302u);
  L.a[2] = __builtin_amdgcn_perm(u[5], u[4], 0x07060302u);
  L.a[3] = __builtin_amdgcn_perm(u[7], u[6], 0x07060302u);
  FragHL f; f.h = H.v; f.l = L.v; return f;
}

__device__ __forceinline__ void ld8(const uint32_t* p, uint32_t* u) {
  const uint4 a = *reinterpret_cast<const uint4*>(p);
  const uint4 b = *reinterpret_cast<const uint4*>(p + 4);
  u[0]=a.x; u[1]=a.y; u[2]=a.z; u[3]=a.w;
  u[4]=b.x; u[5]=b.y; u[6]=b.z; u[7]=b.w;
}

__device__ __forceinline__ bf16x8 asbf(uint4 u) {
  union { uint4 a; bf16x8 v; } c; c.a = u; return c.v;
}

__device__ __forceinline__ f32x4 mfma16(bf16x8 a, bf16x8 b, f32x4 c) {
  return __builtin_amdgcn_mfma_f32_16x16x32_bf16(a, b, c, 0, 0, 0);
}

// ---------------------------------------------------------------------------
// p0: pack weights once into fragment-ready hi/lo bf16-pair arrays in ws.
// ---------------------------------------------------------------------------
__global__ __launch_bounds__(256) void p0_pack(
    const float* __restrict__ w1, const float* __restrict__ w2,
    const float* __restrict__ kp, uint32_t* __restrict__ wp)
{
  const int id = blockIdx.x*256 + threadIdx.x;   // pair index, 0..40959
  const float* src; uint32_t *dh, *dl; int p;
  if (id < 16384)      { src = w1; p = id;         dh = wp;         dl = wp+16384; }
  else if (id < 32768) { src = w2; p = id-16384;   dh = wp+32768;   dl = wp+49152; }
  else                 { src = kp; p = id-32768;   dh = wp+65536;   dl = wp+73728; }
  const float x0 = src[2*p], x1 = src[2*p+1];
  const uint32_t b0 = __float_as_uint(x0), b1 = __float_as_uint(x1);
  const float l0f = x0 - __uint_as_float(b0 & 0xFFFF0000u);
  const float l1f = x1 - __uint_as_float(b1 & 0xFFFF0000u);
  dh[p] = (b0 >> 16) | ((b1 >> 16) << 16);
  dl[p] = (__float_as_uint(l0f) >> 16) | ((__float_as_uint(l1f) >> 16) << 16);
}

// ---------------------------------------------------------------------------
// Phase 1 (MFMA, unchanged from r7)
// ---------------------------------------------------------------------------
__global__ __launch_bounds__(256, 2) void p1_fused(
    const int* __restrict__ seq,
    const float* __restrict__ embed_w,
    const uint32_t* __restrict__ wp,
    const float* __restrict__ ff_b1, const float* __restrict__ ff_b2,
    const float* __restrict__ ln_g, const float* __restrict__ ln_b,
    uint32_t* __restrict__ knp_all, float* __restrict__ norm_all)
{
  __shared__ __align__(16) uint32_t h_p[64*HS];   // packed h, later packed hn
  __shared__ __align__(16) uint32_t u_p[64*HS];   // packed u (one 128-col half)
  __shared__ float part1[256], part2[256];
  __shared__ float mul[64], rsl[64];
  __shared__ int sid[64];

  const int tid  = threadIdx.x;
  const int lane = tid & 63;
  const int w    = __builtin_amdgcn_readfirstlane(tid >> 6);
  const int q4   = lane >> 4;
  const int m16  = lane & 15;
  const int tile0 = blockIdx.x * 64;

  const uint32_t* w1h = wp;
  const uint32_t* w1l = wp + 16384;
  const uint32_t* w2h = wp + 32768;
  const uint32_t* w2l = wp + 49152;
  const uint32_t* kph = wp + 65536;
  const uint32_t* kpl = wp + 73728;

  if (tid < 64) sid[tid] = seq[tile0 + tid];
  __syncthreads();

  { // embed gather -> packed h_p[token][feature]
    const int t = tid >> 2, part = tid & 3;
    const float4* erow =
        reinterpret_cast<const float4*>(embed_w + (size_t)sid[t]*Hn) + part*8;
    #pragma unroll
    for (int c = 0; c < 8; ++c) {
      float4 v = erow[c];
      int j = part*32 + c*4;
      h_p[t*HS+j+0] = packhl(v.x); h_p[t*HS+j+1] = packhl(v.y);
      h_p[t*HS+j+2] = packhl(v.z); h_p[t*HS+j+3] = packhl(v.w);
    }
  }
  __syncthreads();

  f32x4 acc2[4][2];
  #pragma unroll
  for (int tt=0;tt<4;++tt)
    #pragma unroll
    for (int ct=0;ct<2;++ct) acc2[tt][ct] = (f32x4){0.f,0.f,0.f,0.f};

  #pragma unroll 1
  for (int ho=0; ho<2; ++ho) {
    #pragma unroll 1
    for (int tt=0; tt<4; ++tt) {
      FragHL fa[4];
      #pragma unroll
      for (int kk=0;kk<4;++kk) {
        uint32_t ua[8];
        ld8(&h_p[(16*tt+m16)*HS + 32*kk + 8*q4], ua);
        fa[kk] = mkfrag(ua);
      }
      #pragma unroll
      for (int ct=0; ct<2; ++ct) {
        const int ob = 128*ho + 32*w + 16*ct;
        f32x4 a = (f32x4){0.f,0.f,0.f,0.f};
        #pragma unroll
        for (int kk=0;kk<4;++kk) {
          const size_t wi = (size_t)(ob+m16)*64 + 16*kk + 4*q4;
          bf16x8 bh = asbf(*reinterpret_cast<const uint4*>(&w1h[wi]));
          bf16x8 bl = asbf(*reinterpret_cast<const uint4*>(&w1l[wi]));
          a = mfma16(fa[kk].h, bh, a);
          a = mfma16(fa[kk].h, bl, a);
          a = mfma16(fa[kk].l, bh, a);
        }
        const float bb = ff_b1[ob + m16];
        #pragma unroll
        for (int reg=0;reg<4;++reg) {
          float uv = fmaxf(a[reg] + bb, 0.f);
          u_p[(16*tt+4*q4+reg)*HS + 32*w + 16*ct + m16] = packhl(uv);
        }
      }
    }
    __syncthreads();
    #pragma unroll 1
    for (int tt=0; tt<4; ++tt) {
      FragHL fu[4];
      #pragma unroll
      for (int kk=0;kk<4;++kk) {
        uint32_t ua[8];
        ld8(&u_p[(16*tt+m16)*HS + 32*kk + 8*q4], ua);
        fu[kk] = mkfrag(ua);
      }
      #pragma unroll
      for (int ct=0; ct<2; ++ct) {
        const int ib = 32*w + 16*ct;
        f32x4 a = acc2[tt][ct];
        #pragma unroll
        for (int kk=0;kk<4;++kk) {
          const size_t wi = (size_t)(ib+m16)*128 + 64*ho + 16*kk + 4*q4;
          bf16x8 bh = asbf(*reinterpret_cast<const uint4*>(&w2h[wi]));
          bf16x8 bl = asbf(*reinterpret_cast<const uint4*>(&w2l[wi]));
          a = mfma16(fu[kk].h, bh, a);
          a = mfma16(fu[kk].h, bl, a);
          a = mfma16(fu[kk].l, bh, a);
        }
        acc2[tt][ct] = a;
      }
    }
    __syncthreads();
  }

  // ---- bias + residual; LN partials ----
  float xx[4][2][4];
  #pragma unroll
  for (int tt=0;tt<4;++tt)
    #pragma unroll
    for (int ct=0;ct<2;++ct) {
      const int col = 32*w + 16*ct + m16;
      const float b2 = ff_b2[col];
      #pragma unroll
      for (int reg=0;reg<4;++reg) {
        const float hval = unpackhl(h_p[(16*tt+4*q4+reg)*HS + col]);
        xx[tt][ct][reg] = acc2[tt][ct][reg] + b2 + hval;
      }
    }
  #pragma unroll
  for (int tt=0;tt<4;++tt)
    #pragma unroll
    for (int reg=0;reg<4;++reg) {
      float s1 = xx[tt][0][reg] + xx[tt][1][reg];
      float s2 = xx[tt][0][reg]*xx[tt][0][reg] + xx[tt][1][reg]*xx[tt][1][reg];
      s1 += __shfl_xor(s1,1); s1 += __shfl_xor(s1,2);
      s1 += __shfl_xor(s1,4); s1 += __shfl_xor(s1,8);
      s2 += __shfl_xor(s2,1); s2 += __shfl_xor(s2,2);
      s2 += __shfl_xor(s2,4); s2 += __shfl_xor(s2,8);
      if (m16==0) {
        part1[w*64 + 16*tt+4*q4+reg] = s1;
        part2[w*64 + 16*tt+4*q4+reg] = s2;
      }
    }
  __syncthreads();
  if (tid < 64) {
    const float mu = (part1[tid]+part1[64+tid]+part1[128+tid]+part1[192+tid])*(1.0f/128.0f);
    const float ms = (part2[tid]+part2[64+tid]+part2[128+tid]+part2[192+tid])*(1.0f/128.0f);
    mul[tid] = mu;
    rsl[tid] = rsqrtf(ms - mu*mu + 1e-5f);
  }
  __syncthreads();

  #pragma unroll
  for (int tt=0;tt<4;++tt)
    #pragma unroll
    for (int ct=0;ct<2;++ct) {
      const int col = 32*w + 16*ct + m16;
      const float g = ln_g[col], bb = ln_b[col];
      #pragma unroll
      for (int reg=0;reg<4;++reg) {
        const int tok = 16*tt+4*q4+reg;
        const float hn = (xx[tt][ct][reg] - mul[tok])*rsl[tok]*g + bb;
        h_p[tok*HS + col] = packhl(hn);
      }
    }
  __syncthreads();

  // ---- k projection ----
  f32x4 ak[4][2];
  #pragma unroll 1
  for (int tt=0;tt<4;++tt) {
    FragHL fh[4];
    #pragma unroll
    for (int kk=0;kk<4;++kk) {
      uint32_t ua[8];
      ld8(&h_p[(16*tt+m16)*HS + 32*kk + 8*q4], ua);
      fh[kk] = mkfrag(ua);
    }
    #pragma unroll
    for (int ct=0;ct<2;++ct) {
      const int ob = 32*w + 16*ct;
      f32x4 a = (f32x4){0.f,0.f,0.f,0.f};
      #pragma unroll
      for (int kk=0;kk<4;++kk) {
        const size_t wi = (size_t)(ob+m16)*64 + 16*kk + 4*q4;
        bf16x8 bh = asbf(*reinterpret_cast<const uint4*>(&kph[wi]));
        bf16x8 bl = asbf(*reinterpret_cast<const uint4*>(&kpl[wi]));
        a = mfma16(fh[kk].h, bh, a);
        a = mfma16(fh[kk].h, bl, a);
        a = mfma16(fh[kk].l, bh, a);
      }
      ak[tt][ct] = a;
    }
  }
  #pragma unroll
  for (int tt=0;tt<4;++tt)
    #pragma unroll
    for (int reg=0;reg<4;++reg) {
      float s = ak[tt][0][reg]*ak[tt][0][reg] + ak[tt][1][reg]*ak[tt][1][reg];
      s += __shfl_xor(s,1); s += __shfl_xor(s,2);
      s += __shfl_xor(s,4); s += __shfl_xor(s,8);
      if (m16==0) part1[w*64 + 16*tt+4*q4+reg] = s;
    }
  __syncthreads();
  if (tid < 64) {
    const float nn = part1[tid]+part1[64+tid]+part1[128+tid]+part1[192+tid];
    const float nrm = sqrtf(nn);
    norm_all[tile0 + tid] = nrm;
    mul[tid] = 1.0f / fmaxf(nrm, 1e-12f);
  }
  __syncthreads();
  #pragma unroll
  for (int tt=0;tt<4;++tt)
    #pragma unroll
    for (int ct=0;ct<2;++ct) {
      const int col = 32*w + 16*ct + m16;
      #pragma unroll
      for (int reg=0;reg<4;++reg) {
        const int tok = 16*tt+4*q4+reg;
        knp_all[(size_t)(tile0+tok)*Hn + col] = packhl(ak[tt][ct][reg]*mul[tok]);
      }
    }
}

// ---------------------------------------------------------------------------
// Phase 2 (r8): chunked WY scan, MFMA, 2 barriers/chunk.
// Per chunk:  [gpf issue][Gram wv4-7 + A all] B1
//             [wv0: register-resident serial | wv1-4: stage ch+1 | wv1-7:
//              prefetch E B-frags into regs] B2  [E: M += AD^T Kn]  loop.
// vp0L (A->serial) and adL (serial->E) are separate arrays; kn double-buffered.
// ---------------------------------------------------------------------------
__global__ __launch_bounds__(512, 2) void p2_scan(
    const uint32_t* __restrict__ knp_all, const float* __restrict__ norm_all,
    float* __restrict__ read_ws)
{
  const int tid  = threadIdx.x;
  const int lane = tid & 63;
  const int wv   = __builtin_amdgcn_readfirstlane(tid >> 6);  // 0..7
  const int q    = lane >> 4;
  const int m    = lane & 15;
  const int b    = blockIdx.x;

  __shared__ __align__(16) uint32_t kn_p[2*CC*KP];  // double-buffered packed kn
  __shared__ __align__(16) float    vp0L[CC*VS];    // A -> serial
  __shared__ __align__(16) float    adL [CC*VS];    // serial -> E
  __shared__ __align__(16) float    Gt  [CC*GS];
  __shared__ __align__(16) uint32_t msc [8*MSW];
  __shared__ float nrm_l[2*CC];

  f32x4 Macc[8];
  #pragma unroll
  for (int ct=0; ct<8; ++ct) Macc[ct] = (f32x4){0.f,0.f,0.f,0.f};

  const uint32_t* knb = knp_all + (size_t)b*Ln*Hn;
  const float*    nb  = norm_all + (size_t)b*Ln;

  { // stage chunk 0 into buffer 0
    if (tid < 256) {
      const int t = tid>>3, g = tid&7;
      const uint4* src = reinterpret_cast<const uint4*>(knb + t*Hn + g*16);
      uint4* dst = reinterpret_cast<uint4*>(&kn_p[t*KP + g*16]);
      dst[0]=src[0]; dst[1]=src[1]; dst[2]=src[2]; dst[3]=src[3];
    }
    if (tid >= 256 && tid < 256+CC) nrm_l[tid-256] = nb[tid-256];
  }
  __syncthreads();

  #pragma unroll 1
  for (int ch=0; ch<NCH; ++ch) {
    const int cur = ch & 1;
    const uint32_t* knc = &kn_p[cur*CC*KP];
    const bool havenext = (ch+1 < NCH);

    // issue global prefetch for ch+1 (waves 1-4 + nrm threads)
    uint4 pfa, pfb, pfc, pfd; float pfn = 0.f;
    if (havenext) {
      if (tid >= 64 && tid < 320) {
        const int idx = tid-64, t = idx>>3, g = idx&7;
        const uint4* src = reinterpret_cast<const uint4*>(
            knb + (size_t)(ch+1)*CC*Hn + t*Hn + g*16);
        pfa=src[0]; pfb=src[1]; pfc=src[2]; pfd=src[3];
      }
      if (tid >= 320 && tid < 320+CC) pfn = nb[(ch+1)*CC + (tid-320)];
    }

    // ---- Gram via MFMA on waves 4-7 ----
    if (wv >= 4) {
      const int ti = (wv-4)>>1, si = (wv-4)&1;
      f32x4 g4 = (f32x4){0.f,0.f,0.f,0.f};
      #pragma unroll
      for (int kk=0; kk<4; ++kk) {
        uint32_t ua[8], ub[8];
        ld8(&knc[(16*ti+m)*KP + 32*kk + 8*q], ua);
        ld8(&knc[(16*si+m)*KP + 32*kk + 8*q], ub);
        FragHL fa = mkfrag(ua), fb = mkfrag(ub);
        g4 = mfma16(fa.h, fb.h, g4);
        g4 = mfma16(fa.h, fb.l, g4);
        g4 = mfma16(fa.l, fb.h, g4);
      }
      #pragma unroll
      for (int reg=0; reg<4; ++reg)
        Gt[(16*ti + 4*q + reg)*GS + 16*si + m] = g4[reg];
    }

    // ---- Phase A: vp0 = M * Kn^T (all waves) ----
    {
      f32x4 v0 = (f32x4){0.f,0.f,0.f,0.f};
      f32x4 v1 = (f32x4){0.f,0.f,0.f,0.f};
      uint32_t* mybase = &msc[wv*MSW];
      #pragma unroll
      for (int kk=0; kk<4; ++kk) {
        #pragma unroll
        for (int c2=0; c2<2; ++c2) {
          const int ct = 2*kk + c2;
          #pragma unroll
          for (int reg=0; reg<4; ++reg)
            mybase[(4*q+reg)*MSR + 16*c2 + m] = packhl(Macc[ct][reg]);
        }
        uint32_t ua[8], ub[8];
        ld8(&mybase[m*MSR + 8*q], ua);
        FragHL fa = mkfrag(ua);
        ld8(&knc[m*KP + 32*kk + 8*q], ub);
        FragHL fb = mkfrag(ub);
        v0 = mfma16(fa.h, fb.h, v0);
        v0 = mfma16(fa.h, fb.l, v0);
        v0 = mfma16(fa.l, fb.h, v0);
        ld8(&knc[(16+m)*KP + 32*kk + 8*q], ub);
        fb = mkfrag(ub);
        v1 = mfma16(fa.h, fb.h, v1);
        v1 = mfma16(fa.h, fb.l, v1);
        v1 = mfma16(fa.l, fb.h, v1);
      }
      *reinterpret_cast<f32x4*>(&vp0L[m*VS + 16*wv + 4*q]) = v0;
      *reinterpret_cast<f32x4*>(&vp0L[(16+m)*VS + 16*wv + 4*q]) = v1;
    }
    __syncthreads();                       // B1: vp0L + Gt ready

    uint32_t ebuf[64];
    if (wv==0) {
      // ---- serial d-recurrence, fully register-prefetched ----
      float b0r[CC], b1r[CC], gr[CC];
      const float nrmv = nrm_l[cur*CC + (lane&31)];
      #pragma unroll
      for (int t=0;t<CC;++t) {
        gr[t] = Gt[t*GS + (lane&31)];
        const float nrm = rdlane(nrmv, t);
        b0r[t] = nrm*unpackhl(knc[t*KP + lane])      - vp0L[t*VS + lane];
        b1r[t] = nrm*unpackhl(knc[t*KP + 64 + lane]) - vp0L[t*VS + 64 + lane];
      }
      const float vq0 = vp0L[(CC-1)*VS + lane];
      const float vq1 = vp0L[(CC-1)*VS + 64 + lane];
      float ad0[CC], ad1[CC];
      #pragma unroll
      for (int t=0;t<CC;++t) {
        float a0e = b0r[t], a1e = b1r[t];
        float a0o = 0.f, a1o = 0.f;
        #pragma unroll
        for (int s=0; s<t; ++s) {                   // static: only s<t emitted
          const float g = rdlane(gr[t], s);
          if (s & 1) { a0o -= g*ad0[s]; a1o -= g*ad1[s]; }
          else       { a0e -= g*ad0[s]; a1e -= g*ad1[s]; }
        }
        const float acc0 = a0e + a0o;
        const float acc1 = a1e + a1o;
        float sq = acc0*acc0 + acc1*acc1;
        sq += __shfl_xor(sq,32); sq += __shfl_xor(sq,16); sq += __shfl_xor(sq,8);
        sq += __shfl_xor(sq,4);  sq += __shfl_xor(sq,2);  sq += __shfl_xor(sq,1);
        const float nrm = rdlane(nrmv, t);
        if (ch==NCH-1 && t==CC-1) {
          // read = nrm * (vp0 + sum_s g ad_s) = nrm*(vq + b - acc)
          read_ws[b*Hn + lane]      = nrm*(vq0 + b0r[t] - acc0);
          read_ws[b*Hn + 64 + lane] = nrm*(vq1 + b1r[t] - acc1);
        } else {
          const float at = (sqrtf(sq) >= 0.4f*nrm) ? LAMBDA_ : 0.f;
          ad0[t] = at*acc0; ad1[t] = at*acc1;
          adL[t*VS + lane]      = ad0[t];
          adL[t*VS + 64 + lane] = ad1[t];
        }
      }
    } else {
      if (havenext) {
        // stage prefetched chunk ch+1 into idle buffer (waves 1-4)
        if (tid >= 64 && tid < 320) {
          const int idx = tid-64, t = idx>>3, g = idx&7;
          uint4* dst = reinterpret_cast<uint4*>(
              &kn_p[(1-cur)*CC*KP + t*KP + g*16]);
          dst[0]=pfa; dst[1]=pfb; dst[2]=pfc; dst[3]=pfd;
        }
        if (tid >= 320 && tid < 320+CC) nrm_l[(1-cur)*CC + (tid-320)] = pfn;
        // prefetch E B-fragments (the 4-way-conflicted reads) into registers
        #pragma unroll
        for (int ct=0; ct<8; ++ct)
          #pragma unroll
          for (int j=0;j<8;++j)
            ebuf[ct*8+j] = knc[(8*q+j)*KP + 16*ct + m];
      }
    }
    __syncthreads();                       // B2: adL + staged tile ready
    if (ch==NCH-1) break;

    // ---- Phase E: M += AD^T * Kn ----
    {
      uint32_t ap[8];
      #pragma unroll
      for (int j=0;j<8;++j)
        ap[j] = packhl(adL[(8*q+j)*VS + 16*wv + m]);
      FragHL fa = mkfrag(ap);
      #pragma unroll
      for (int ct=0; ct<8; ++ct) {
        uint32_t bu[8];
        if (wv==0) {
          #pragma unroll
          for (int j=0;j<8;++j)
            bu[j] = knc[(8*q+j)*KP + 16*ct + m];
        } else {
          #pragma unroll
          for (int j=0;j<8;++j)
            bu[j] = ebuf[ct*8+j];
        }
        FragHL fb = mkfrag(bu);
        Macc[ct] = mfma16(fa.h, fb.h, Macc[ct]);
        Macc[ct] = mfma16(fa.h, fb.l, Macc[ct]);
        Macc[ct] = mfma16(fa.l, fb.h, Macc[ct]);
      }
    }
  }
}

// ---------------------------------------------------------------------------
// Phase 3a: o1 = read @ rp_w^T + rp_b
// ---------------------------------------------------------------------------
__global__ __launch_bounds__(128) void p3a(
    const float* __restrict__ read_ws, const float* __restrict__ rp_w,
    const float* __restrict__ rp_b, float* __restrict__ o1_ws)
{
  __shared__ float rd[128];
  const int b = blockIdx.x, t = threadIdx.x;
  rd[t] = read_ws[b*Hn + t];
  __syncthreads();
  float acc = rp_b[t];
  const float* wr = rp_w + t*Hn;
  #pragma unroll 4
  for (int i = 0; i < Hn; ++i) acc += rd[i]*wr[i];
  o1_ws[b*Hn + t] = acc;
}

// ---------------------------------------------------------------------------
// Phase 3b: out = o1 @ out_w^T + out_b
// ---------------------------------------------------------------------------
__global__ __launch_bounds__(256) void p3b(
    const float* __restrict__ o1_ws, const float* __restrict__ out_w,
    const float* __restrict__ out_b, float* __restrict__ out)
{
  __shared__ __align__(16) float o1[8192];       // [64][128]
  const int tid = threadIdx.x;
  #pragma unroll
  for (int c = 0; c < 32; ++c) o1[c*256+tid] = o1_ws[c*256+tid];
  __syncthreads();
  const int v = blockIdx.x*256 + tid;            // 125*256 == 32000
  float acc[64];
  const float ob = out_b[v];
  #pragma unroll
  for (int bb = 0; bb < 64; ++bb) acc[bb] = ob;
  const float4* wrow = reinterpret_cast<const float4*>(out_w + (size_t)v*Hn);
  #pragma unroll 1
  for (int r4 = 0; r4 < 32; ++r4) {
    const float4 wv = wrow[r4];
    #pragma unroll
    for (int bb = 0; bb < 64; ++bb) {
      const float4 ov = *reinterpret_cast<const float4*>(&o1[bb*Hn + r4*4]);
      acc[bb] += wv.x*ov.x + wv.y*ov.y + wv.z*ov.z + wv.w*ov.w;
    }
  }
  #pragma unroll
  for (int bb = 0; bb < 64; ++bb) out[(size_t)bb*Vn + v] = acc[bb];
}

// ---------------------------------------------------------------------------
extern "C" void kernel_launch(void* const* d_in, const int* in_sizes, int n_in,
                              void* d_out, int out_size, void* d_ws, size_t ws_size,
                              hipStream_t stream)
{
  const int*   seq     = (const int*)  d_in[0];
  const float* embed_w = (const float*)d_in[1];
  const float* ff_w1   = (const float*)d_in[2];
  const float* ff_b1   = (const float*)d_in[3];
  const float* ff_w2   = (const float*)d_in[4];
  const float* ff_b2   = (const float*)d_in[5];
  const float* ln_g    = (const float*)d_in[6];
  const float* ln_b    = (const float*)d_in[7];
  const float* kp_w    = (const float*)d_in[8];
  const float* rp_w    = (const float*)d_in[9];
  const float* rp_b    = (const float*)d_in[10];
  const float* out_w   = (const float*)d_in[11];
  const float* out_b   = (const float*)d_in[12];

  float* ws          = (float*)d_ws;
  uint32_t* knp_all  = (uint32_t*)ws;                 // B*L*H u32 (packed hi/lo)
  float* norm_all    = ws + (size_t)Bn*Ln*Hn;         // B*L
  float* read_ws     = norm_all + (size_t)Bn*Ln;      // B*H
  float* o1_ws       = read_ws + Bn*Hn;               // B*H
  uint32_t* wp       = (uint32_t*)(o1_ws + Bn*Hn);    // 81920 u32 packed weights

  p0_pack<<<dim3(160), dim3(256), 0, stream>>>(ff_w1, ff_w2, kp_w, wp);
  p1_fused<<<dim3(2048), dim3(256), 0, stream>>>(
      seq, embed_w, wp, ff_b1, ff_b2, ln_g, ln_b, knp_all, norm_all);
  p2_scan<<<dim3(64), dim3(512), 0, stream>>>(knp_all, norm_all, read_ws);
  p3a<<<dim3(64), dim3(128), 0, stream>>>(read_ws, rp_w, rp_b, o1_ws);
  p3b<<<dim3(125), dim3(256), 0, stream>>>(o1_ws, out_w, out_b, (float*)d_out);
}

// Round 9
// 1012.554 us; speedup vs baseline: 1.1193x; 1.1193x over previous
//
#include <hip/hip_runtime.h>
#include <hip/hip_bf16.h>
#include <stdint.h>

#define Bn 64
#define Ln 2048
#define Hn 128
#define Vn 32000
#define THn 256            // 2*H
#define LAMBDA_ (1.0f/2048.0f)
#define CC 32              // scan chunk size
#define NCH (Ln/CC)        // 64 chunks
#define KP  132            // p2 kn_p row stride (uints)
#define VS  132            // p2 vp0L/adL row stride (floats)
#define GS  36             // p2 Gt row stride
#define MSR 36             // p2 m_scratch row stride (uints)
#define MSW 576            // p2 m_scratch per-wave size (16*36)
#define HS  132            // p1 h_p/u_p row stride (uints)

typedef short bf16x8 __attribute__((ext_vector_type(8)));
typedef float f32x4  __attribute__((ext_vector_type(4)));

__device__ __forceinline__ float rdlane(float v, int s) {
  return __int_as_float(__builtin_amdgcn_readlane(__float_as_int(v), s));
}

// pack fp32 -> (bf16 hi in low16, bf16 lo in high16), truncation split
__device__ __forceinline__ uint32_t packhl(float x) {
  uint32_t bx = __float_as_uint(x);
  float hf = __uint_as_float(bx & 0xFFFF0000u);
  uint32_t bl = __float_as_uint(x - hf);
  return (bx >> 16) | (bl & 0xFFFF0000u);
}
__device__ __forceinline__ float unpackhl(uint32_t u) {
  return __uint_as_float(u << 16) + __uint_as_float(u & 0xFFFF0000u);
}

struct FragHL { bf16x8 h; bf16x8 l; };
__device__ __forceinline__ FragHL mkfrag(const uint32_t* u) {
  union { uint32_t a[4]; bf16x8 v; } H, L;
  H.a[0] = __builtin_amdgcn_perm(u[1], u[0], 0x05040100u);
  H.a[1] = __builtin_amdgcn_perm(u[3], u[2], 0x05040100u);
  H.a[2] = __builtin_amdgcn_perm(u[5], u[4], 0x05040100u);
  H.a[3] = __builtin_amdgcn_perm(u[7], u[6], 0x05040100u);
  L.a[0] = __builtin_amdgcn_perm(u[1], u[0], 0x07060302u);
  L.a[1] = __builtin_amdgcn_perm(u[3], u[2], 0x07060302u);
  L.a[2] = __builtin_amdgcn_perm(u[5], u[4], 0x07060302u);
  L.a[3] = __builtin_amdgcn_perm(u[7], u[6], 0x07060302u);
  FragHL f; f.h = H.v; f.l = L.v; return f;
}

__device__ __forceinline__ void ld8(const uint32_t* p, uint32_t* u) {
  const uint4 a = *reinterpret_cast<const uint4*>(p);
  const uint4 b = *reinterpret_cast<const uint4*>(p + 4);
  u[0]=a.x; u[1]=a.y; u[2]=a.z; u[3]=a.w;
  u[4]=b.x; u[5]=b.y; u[6]=b.z; u[7]=b.w;
}

__device__ __forceinline__ bf16x8 asbf(uint4 u) {
  union { uint4 a; bf16x8 v; } c; c.a = u; return c.v;
}

__device__ __forceinline__ f32x4 mfma16(bf16x8 a, bf16x8 b, f32x4 c) {
  return __builtin_amdgcn_mfma_f32_16x16x32_bf16(a, b, c, 0, 0, 0);
}

// ---------------------------------------------------------------------------
// p0: pack weights once into fragment-ready hi/lo bf16-pair arrays in ws.
// ---------------------------------------------------------------------------
__global__ __launch_bounds__(256) void p0_pack(
    const float* __restrict__ w1, const float* __restrict__ w2,
    const float* __restrict__ kp, uint32_t* __restrict__ wp)
{
  const int id = blockIdx.x*256 + threadIdx.x;   // pair index, 0..40959
  const float* src; uint32_t *dh, *dl; int p;
  if (id < 16384)      { src = w1; p = id;         dh = wp;         dl = wp+16384; }
  else if (id < 32768) { src = w2; p = id-16384;   dh = wp+32768;   dl = wp+49152; }
  else                 { src = kp; p = id-32768;   dh = wp+65536;   dl = wp+73728; }
  const float x0 = src[2*p], x1 = src[2*p+1];
  const uint32_t b0 = __float_as_uint(x0), b1 = __float_as_uint(x1);
  const float l0f = x0 - __uint_as_float(b0 & 0xFFFF0000u);
  const float l1f = x1 - __uint_as_float(b1 & 0xFFFF0000u);
  dh[p] = (b0 >> 16) | ((b1 >> 16) << 16);
  dl[p] = (__float_as_uint(l0f) >> 16) | ((__float_as_uint(l1f) >> 16) << 16);
}

// ---------------------------------------------------------------------------
// Phase 1 (MFMA, unchanged from r7)
// ---------------------------------------------------------------------------
__global__ __launch_bounds__(256, 2) void p1_fused(
    const int* __restrict__ seq,
    const float* __restrict__ embed_w,
    const uint32_t* __restrict__ wp,
    const float* __restrict__ ff_b1, const float* __restrict__ ff_b2,
    const float* __restrict__ ln_g, const float* __restrict__ ln_b,
    uint32_t* __restrict__ knp_all, float* __restrict__ norm_all)
{
  __shared__ __align__(16) uint32_t h_p[64*HS];   // packed h, later packed hn
  __shared__ __align__(16) uint32_t u_p[64*HS];   // packed u (one 128-col half)
  __shared__ float part1[256], part2[256];
  __shared__ float mul[64], rsl[64];
  __shared__ int sid[64];

  const int tid  = threadIdx.x;
  const int lane = tid & 63;
  const int w    = __builtin_amdgcn_readfirstlane(tid >> 6);
  const int q4   = lane >> 4;
  const int m16  = lane & 15;
  const int tile0 = blockIdx.x * 64;

  const uint32_t* w1h = wp;
  const uint32_t* w1l = wp + 16384;
  const uint32_t* w2h = wp + 32768;
  const uint32_t* w2l = wp + 49152;
  const uint32_t* kph = wp + 65536;
  const uint32_t* kpl = wp + 73728;

  if (tid < 64) sid[tid] = seq[tile0 + tid];
  __syncthreads();

  { // embed gather -> packed h_p[token][feature]
    const int t = tid >> 2, part = tid & 3;
    const float4* erow =
        reinterpret_cast<const float4*>(embed_w + (size_t)sid[t]*Hn) + part*8;
    #pragma unroll
    for (int c = 0; c < 8; ++c) {
      float4 v = erow[c];
      int j = part*32 + c*4;
      h_p[t*HS+j+0] = packhl(v.x); h_p[t*HS+j+1] = packhl(v.y);
      h_p[t*HS+j+2] = packhl(v.z); h_p[t*HS+j+3] = packhl(v.w);
    }
  }
  __syncthreads();

  f32x4 acc2[4][2];
  #pragma unroll
  for (int tt=0;tt<4;++tt)
    #pragma unroll
    for (int ct=0;ct<2;++ct) acc2[tt][ct] = (f32x4){0.f,0.f,0.f,0.f};

  #pragma unroll 1
  for (int ho=0; ho<2; ++ho) {
    #pragma unroll 1
    for (int tt=0; tt<4; ++tt) {
      FragHL fa[4];
      #pragma unroll
      for (int kk=0;kk<4;++kk) {
        uint32_t ua[8];
        ld8(&h_p[(16*tt+m16)*HS + 32*kk + 8*q4], ua);
        fa[kk] = mkfrag(ua);
      }
      #pragma unroll
      for (int ct=0; ct<2; ++ct) {
        const int ob = 128*ho + 32*w + 16*ct;
        f32x4 a = (f32x4){0.f,0.f,0.f,0.f};
        #pragma unroll
        for (int kk=0;kk<4;++kk) {
          const size_t wi = (size_t)(ob+m16)*64 + 16*kk + 4*q4;
          bf16x8 bh = asbf(*reinterpret_cast<const uint4*>(&w1h[wi]));
          bf16x8 bl = asbf(*reinterpret_cast<const uint4*>(&w1l[wi]));
          a = mfma16(fa[kk].h, bh, a);
          a = mfma16(fa[kk].h, bl, a);
          a = mfma16(fa[kk].l, bh, a);
        }
        const float bb = ff_b1[ob + m16];
        #pragma unroll
        for (int reg=0;reg<4;++reg) {
          float uv = fmaxf(a[reg] + bb, 0.f);
          u_p[(16*tt+4*q4+reg)*HS + 32*w + 16*ct + m16] = packhl(uv);
        }
      }
    }
    __syncthreads();
    #pragma unroll 1
    for (int tt=0; tt<4; ++tt) {
      FragHL fu[4];
      #pragma unroll
      for (int kk=0;kk<4;++kk) {
        uint32_t ua[8];
        ld8(&u_p[(16*tt+m16)*HS + 32*kk + 8*q4], ua);
        fu[kk] = mkfrag(ua);
      }
      #pragma unroll
      for (int ct=0; ct<2; ++ct) {
        const int ib = 32*w + 16*ct;
        f32x4 a = acc2[tt][ct];
        #pragma unroll
        for (int kk=0;kk<4;++kk) {
          const size_t wi = (size_t)(ib+m16)*128 + 64*ho + 16*kk + 4*q4;
          bf16x8 bh = asbf(*reinterpret_cast<const uint4*>(&w2h[wi]));
          bf16x8 bl = asbf(*reinterpret_cast<const uint4*>(&w2l[wi]));
          a = mfma16(fu[kk].h, bh, a);
          a = mfma16(fu[kk].h, bl, a);
          a = mfma16(fu[kk].l, bh, a);
        }
        acc2[tt][ct] = a;
      }
    }
    __syncthreads();
  }

  // ---- bias + residual; LN partials ----
  float xx[4][2][4];
  #pragma unroll
  for (int tt=0;tt<4;++tt)
    #pragma unroll
    for (int ct=0;ct<2;++ct) {
      const int col = 32*w + 16*ct + m16;
      const float b2 = ff_b2[col];
      #pragma unroll
      for (int reg=0;reg<4;++reg) {
        const float hval = unpackhl(h_p[(16*tt+4*q4+reg)*HS + col]);
        xx[tt][ct][reg] = acc2[tt][ct][reg] + b2 + hval;
      }
    }
  #pragma unroll
  for (int tt=0;tt<4;++tt)
    #pragma unroll
    for (int reg=0;reg<4;++reg) {
      float s1 = xx[tt][0][reg] + xx[tt][1][reg];
      float s2 = xx[tt][0][reg]*xx[tt][0][reg] + xx[tt][1][reg]*xx[tt][1][reg];
      s1 += __shfl_xor(s1,1); s1 += __shfl_xor(s1,2);
      s1 += __shfl_xor(s1,4); s1 += __shfl_xor(s1,8);
      s2 += __shfl_xor(s2,1); s2 += __shfl_xor(s2,2);
      s2 += __shfl_xor(s2,4); s2 += __shfl_xor(s2,8);
      if (m16==0) {
        part1[w*64 + 16*tt+4*q4+reg] = s1;
        part2[w*64 + 16*tt+4*q4+reg] = s2;
      }
    }
  __syncthreads();
  if (tid < 64) {
    const float mu = (part1[tid]+part1[64+tid]+part1[128+tid]+part1[192+tid])*(1.0f/128.0f);
    const float ms = (part2[tid]+part2[64+tid]+part2[128+tid]+part2[192+tid])*(1.0f/128.0f);
    mul[tid] = mu;
    rsl[tid] = rsqrtf(ms - mu*mu + 1e-5f);
  }
  __syncthreads();

  #pragma unroll
  for (int tt=0;tt<4;++tt)
    #pragma unroll
    for (int ct=0;ct<2;++ct) {
      const int col = 32*w + 16*ct + m16;
      const float g = ln_g[col], bb = ln_b[col];
      #pragma unroll
      for (int reg=0;reg<4;++reg) {
        const int tok = 16*tt+4*q4+reg;
        const float hn = (xx[tt][ct][reg] - mul[tok])*rsl[tok]*g + bb;
        h_p[tok*HS + col] = packhl(hn);
      }
    }
  __syncthreads();

  // ---- k projection ----
  f32x4 ak[4][2];
  #pragma unroll 1
  for (int tt=0;tt<4;++tt) {
    FragHL fh[4];
    #pragma unroll
    for (int kk=0;kk<4;++kk) {
      uint32_t ua[8];
      ld8(&h_p[(16*tt+m16)*HS + 32*kk + 8*q4], ua);
      fh[kk] = mkfrag(ua);
    }
    #pragma unroll
    for (int ct=0;ct<2;++ct) {
      const int ob = 32*w + 16*ct;
      f32x4 a = (f32x4){0.f,0.f,0.f,0.f};
      #pragma unroll
      for (int kk=0;kk<4;++kk) {
        const size_t wi = (size_t)(ob+m16)*64 + 16*kk + 4*q4;
        bf16x8 bh = asbf(*reinterpret_cast<const uint4*>(&kph[wi]));
        bf16x8 bl = asbf(*reinterpret_cast<const uint4*>(&kpl[wi]));
        a = mfma16(fh[kk].h, bh, a);
        a = mfma16(fh[kk].h, bl, a);
        a = mfma16(fh[kk].l, bh, a);
      }
      ak[tt][ct] = a;
    }
  }
  #pragma unroll
  for (int tt=0;tt<4;++tt)
    #pragma unroll
    for (int reg=0;reg<4;++reg) {
      float s = ak[tt][0][reg]*ak[tt][0][reg] + ak[tt][1][reg]*ak[tt][1][reg];
      s += __shfl_xor(s,1); s += __shfl_xor(s,2);
      s += __shfl_xor(s,4); s += __shfl_xor(s,8);
      if (m16==0) part1[w*64 + 16*tt+4*q4+reg] = s;
    }
  __syncthreads();
  if (tid < 64) {
    const float nn = part1[tid]+part1[64+tid]+part1[128+tid]+part1[192+tid];
    const float nrm = sqrtf(nn);
    norm_all[tile0 + tid] = nrm;
    mul[tid] = 1.0f / fmaxf(nrm, 1e-12f);
  }
  __syncthreads();
  #pragma unroll
  for (int tt=0;tt<4;++tt)
    #pragma unroll
    for (int ct=0;ct<2;++ct) {
      const int col = 32*w + 16*ct + m16;
      #pragma unroll
      for (int reg=0;reg<4;++reg) {
        const int tok = 16*tt+4*q4+reg;
        knp_all[(size_t)(tile0+tok)*Hn + col] = packhl(ak[tt][ct][reg]*mul[tok]);
      }
    }
}

// ---------------------------------------------------------------------------
// Phase 2 (r9): chunked WY scan, MFMA, 2 barriers/chunk, NO spills.
// Per chunk:  [gpf issue][Gram wv4-7 + A all] B1
//             [wv0: serial (r7-style LDS reads, 4-chain, sqrt-free gate)
//              | wv1-4: stage ch+1 into idle buffer] B2
//             [E: M += AD^T Kn]  loop.
// vp0L (A->serial) and adL (serial->E) separate; kn double-buffered.
// ---------------------------------------------------------------------------
__global__ __launch_bounds__(512, 2) void p2_scan(
    const uint32_t* __restrict__ knp_all, const float* __restrict__ norm_all,
    float* __restrict__ read_ws)
{
  const int tid  = threadIdx.x;
  const int lane = tid & 63;
  const int wv   = __builtin_amdgcn_readfirstlane(tid >> 6);  // 0..7
  const int q    = lane >> 4;
  const int m    = lane & 15;
  const int b    = blockIdx.x;

  __shared__ __align__(16) uint32_t kn_p[2*CC*KP];  // double-buffered packed kn
  __shared__ __align__(16) float    vp0L[CC*VS];    // A -> serial
  __shared__ __align__(16) float    adL [CC*VS];    // serial -> E
  __shared__ __align__(16) float    Gt  [CC*GS];
  __shared__ __align__(16) uint32_t msc [8*MSW];
  __shared__ float nrm_l[2*CC];

  f32x4 Macc[8];
  #pragma unroll
  for (int ct=0; ct<8; ++ct) Macc[ct] = (f32x4){0.f,0.f,0.f,0.f};

  const uint32_t* knb = knp_all + (size_t)b*Ln*Hn;
  const float*    nb  = norm_all + (size_t)b*Ln;

  { // stage chunk 0 into buffer 0
    if (tid < 256) {
      const int t = tid>>3, g = tid&7;
      const uint4* src = reinterpret_cast<const uint4*>(knb + t*Hn + g*16);
      uint4* dst = reinterpret_cast<uint4*>(&kn_p[t*KP + g*16]);
      dst[0]=src[0]; dst[1]=src[1]; dst[2]=src[2]; dst[3]=src[3];
    }
    if (tid >= 256 && tid < 256+CC) nrm_l[tid-256] = nb[tid-256];
  }
  __syncthreads();

  #pragma unroll 1
  for (int ch=0; ch<NCH; ++ch) {
    const int cur = ch & 1;
    const uint32_t* knc = &kn_p[cur*CC*KP];
    const bool havenext = (ch+1 < NCH);

    // issue global prefetch for ch+1 (waves 1-4 + nrm threads)
    uint4 pfa, pfb, pfc, pfd; float pfn = 0.f;
    if (havenext) {
      if (tid >= 64 && tid < 320) {
        const int idx = tid-64, t = idx>>3, g = idx&7;
        const uint4* src = reinterpret_cast<const uint4*>(
            knb + (size_t)(ch+1)*CC*Hn + t*Hn + g*16);
        pfa=src[0]; pfb=src[1]; pfc=src[2]; pfd=src[3];
      }
      if (tid >= 320 && tid < 320+CC) pfn = nb[(ch+1)*CC + (tid-320)];
    }

    // ---- Gram via MFMA on waves 4-7 ----
    if (wv >= 4) {
      const int ti = (wv-4)>>1, si = (wv-4)&1;
      f32x4 g4 = (f32x4){0.f,0.f,0.f,0.f};
      #pragma unroll
      for (int kk=0; kk<4; ++kk) {
        uint32_t ua[8], ub[8];
        ld8(&knc[(16*ti+m)*KP + 32*kk + 8*q], ua);
        ld8(&knc[(16*si+m)*KP + 32*kk + 8*q], ub);
        FragHL fa = mkfrag(ua), fb = mkfrag(ub);
        g4 = mfma16(fa.h, fb.h, g4);
        g4 = mfma16(fa.h, fb.l, g4);
        g4 = mfma16(fa.l, fb.h, g4);
      }
      #pragma unroll
      for (int reg=0; reg<4; ++reg)
        Gt[(16*ti + 4*q + reg)*GS + 16*si + m] = g4[reg];
    }

    // ---- Phase A: vp0 = M * Kn^T (all waves) ----
    {
      f32x4 v0 = (f32x4){0.f,0.f,0.f,0.f};
      f32x4 v1 = (f32x4){0.f,0.f,0.f,0.f};
      uint32_t* mybase = &msc[wv*MSW];
      #pragma unroll
      for (int kk=0; kk<4; ++kk) {
        #pragma unroll
        for (int c2=0; c2<2; ++c2) {
          const int ct = 2*kk + c2;
          #pragma unroll
          for (int reg=0; reg<4; ++reg)
            mybase[(4*q+reg)*MSR + 16*c2 + m] = packhl(Macc[ct][reg]);
        }
        uint32_t ua[8], ub[8];
        ld8(&mybase[m*MSR + 8*q], ua);
        FragHL fa = mkfrag(ua);
        ld8(&knc[m*KP + 32*kk + 8*q], ub);
        FragHL fb = mkfrag(ub);
        v0 = mfma16(fa.h, fb.h, v0);
        v0 = mfma16(fa.h, fb.l, v0);
        v0 = mfma16(fa.l, fb.h, v0);
        ld8(&knc[(16+m)*KP + 32*kk + 8*q], ub);
        fb = mkfrag(ub);
        v1 = mfma16(fa.h, fb.h, v1);
        v1 = mfma16(fa.h, fb.l, v1);
        v1 = mfma16(fa.l, fb.h, v1);
      }
      *reinterpret_cast<f32x4*>(&vp0L[m*VS + 16*wv + 4*q]) = v0;
      *reinterpret_cast<f32x4*>(&vp0L[(16+m)*VS + 16*wv + 4*q]) = v1;
    }
    __syncthreads();                       // B1: vp0L + Gt ready

    if (wv==0) {
      // ---- serial d-recurrence (r7-style per-step LDS reads) ----
      float ad0[CC], ad1[CC], gr[CC];
      #pragma unroll
      for (int t=0;t<CC;++t) gr[t] = Gt[t*GS + (lane&31)];
      const float nrmv = nrm_l[cur*CC + (lane&31)];
      #pragma unroll
      for (int t=0;t<CC;++t) {
        const float nrm = rdlane(nrmv, t);
        const float kn0 = unpackhl(knc[t*KP + lane]);
        const float kn1 = unpackhl(knc[t*KP + 64 + lane]);
        float a0c0 = nrm*kn0 - vp0L[t*VS + lane];
        float a1c0 = nrm*kn1 - vp0L[t*VS + 64 + lane];
        float a0c1=0.f, a0c2=0.f, a0c3=0.f;
        float a1c1=0.f, a1c2=0.f, a1c3=0.f;
        #pragma unroll
        for (int s=0; s<t; ++s) {                   // static: only s<t emitted
          const float g = rdlane(gr[t], s);
          switch (s & 3) {
            case 0: a0c0 -= g*ad0[s]; a1c0 -= g*ad1[s]; break;
            case 1: a0c1 -= g*ad0[s]; a1c1 -= g*ad1[s]; break;
            case 2: a0c2 -= g*ad0[s]; a1c2 -= g*ad1[s]; break;
            default:a0c3 -= g*ad0[s]; a1c3 -= g*ad1[s]; break;
          }
        }
        const float acc0 = (a0c0+a0c1)+(a0c2+a0c3);
        const float acc1 = (a1c0+a1c1)+(a1c2+a1c3);
        float sq = acc0*acc0 + acc1*acc1;
        sq += __shfl_xor(sq,32); sq += __shfl_xor(sq,16); sq += __shfl_xor(sq,8);
        sq += __shfl_xor(sq,4);  sq += __shfl_xor(sq,2);  sq += __shfl_xor(sq,1);
        if (ch==NCH-1 && t==CC-1) {
          // read = M@q, q = nrm*kn; M.kn = nrm*kn - d
          read_ws[b*Hn + lane]      = nrm*(nrm*kn0 - acc0);
          read_ws[b*Hn + 64 + lane] = nrm*(nrm*kn1 - acc1);
        } else {
          // gate: sqrt(sq) >= 0.4*nrm  <=>  sq >= 0.16*nrm*nrm
          const float at = (sq >= 0.16f*nrm*nrm) ? LAMBDA_ : 0.f;
          ad0[t] = at*acc0; ad1[t] = at*acc1;
          adL[t*VS + lane]      = ad0[t];
          adL[t*VS + 64 + lane] = ad1[t];
        }
      }
    } else if (havenext) {
      // stage prefetched chunk ch+1 into idle buffer (waves 1-4 + nrm thrds)
      if (tid >= 64 && tid < 320) {
        const int idx = tid-64, t = idx>>3, g = idx&7;
        uint4* dst = reinterpret_cast<uint4*>(
            &kn_p[(1-cur)*CC*KP + t*KP + g*16]);
        dst[0]=pfa; dst[1]=pfb; dst[2]=pfc; dst[3]=pfd;
      }
      if (tid >= 320 && tid < 320+CC) nrm_l[(1-cur)*CC + (tid-320)] = pfn;
    }
    __syncthreads();                       // B2: adL + staged tile ready
    if (ch==NCH-1) break;

    // ---- Phase E: M += AD^T * Kn ----
    {
      uint32_t ap[8];
      #pragma unroll
      for (int j=0;j<8;++j)
        ap[j] = packhl(adL[(8*q+j)*VS + 16*wv + m]);
      FragHL fa = mkfrag(ap);
      #pragma unroll
      for (int ct=0; ct<8; ++ct) {
        uint32_t bu[8];
        #pragma unroll
        for (int j=0;j<8;++j)
          bu[j] = knc[(8*q+j)*KP + 16*ct + m];
        FragHL fb = mkfrag(bu);
        Macc[ct] = mfma16(fa.h, fb.h, Macc[ct]);
        Macc[ct] = mfma16(fa.h, fb.l, Macc[ct]);
        Macc[ct] = mfma16(fa.l, fb.h, Macc[ct]);
      }
    }
  }
}

// ---------------------------------------------------------------------------
// Phase 3a: o1 = read @ rp_w^T + rp_b
// ---------------------------------------------------------------------------
__global__ __launch_bounds__(128) void p3a(
    const float* __restrict__ read_ws, const float* __restrict__ rp_w,
    const float* __restrict__ rp_b, float* __restrict__ o1_ws)
{
  __shared__ float rd[128];
  const int b = blockIdx.x, t = threadIdx.x;
  rd[t] = read_ws[b*Hn + t];
  __syncthreads();
  float acc = rp_b[t];
  const float* wr = rp_w + t*Hn;
  #pragma unroll 4
  for (int i = 0; i < Hn; ++i) acc += rd[i]*wr[i];
  o1_ws[b*Hn + t] = acc;
}

// ---------------------------------------------------------------------------
// Phase 3b: out = o1 @ out_w^T + out_b
// ---------------------------------------------------------------------------
__global__ __launch_bounds__(256) void p3b(
    const float* __restrict__ o1_ws, const float* __restrict__ out_w,
    const float* __restrict__ out_b, float* __restrict__ out)
{
  __shared__ __align__(16) float o1[8192];       // [64][128]
  const int tid = threadIdx.x;
  #pragma unroll
  for (int c = 0; c < 32; ++c) o1[c*256+tid] = o1_ws[c*256+tid];
  __syncthreads();
  const int v = blockIdx.x*256 + tid;            // 125*256 == 32000
  float acc[64];
  const float ob = out_b[v];
  #pragma unroll
  for (int bb = 0; bb < 64; ++bb) acc[bb] = ob;
  const float4* wrow = reinterpret_cast<const float4*>(out_w + (size_t)v*Hn);
  #pragma unroll 1
  for (int r4 = 0; r4 < 32; ++r4) {
    const float4 wv = wrow[r4];
    #pragma unroll
    for (int bb = 0; bb < 64; ++bb) {
      const float4 ov = *reinterpret_cast<const float4*>(&o1[bb*Hn + r4*4]);
      acc[bb] += wv.x*ov.x + wv.y*ov.y + wv.z*ov.z + wv.w*ov.w;
    }
  }
  #pragma unroll
  for (int bb = 0; bb < 64; ++bb) out[(size_t)bb*Vn + v] = acc[bb];
}

// ---------------------------------------------------------------------------
extern "C" void kernel_launch(void* const* d_in, const int* in_sizes, int n_in,
                              void* d_out, int out_size, void* d_ws, size_t ws_size,
                              hipStream_t stream)
{
  const int*   seq     = (const int*)  d_in[0];
  const float* embed_w = (const float*)d_in[1];
  const float* ff_w1   = (const float*)d_in[2];
  const float* ff_b1   = (const float*)d_in[3];
  const float* ff_w2   = (const float*)d_in[4];
  const float* ff_b2   = (const float*)d_in[5];
  const float* ln_g    = (const float*)d_in[6];
  const float* ln_b    = (const float*)d_in[7];
  const float* kp_w    = (const float*)d_in[8];
  const float* rp_w    = (const float*)d_in[9];
  const float* rp_b    = (const float*)d_in[10];
  const float* out_w   = (const float*)d_in[11];
  const float* out_b   = (const float*)d_in[12];

  float* ws          = (float*)d_ws;
  uint32_t* knp_all  = (uint32_t*)ws;                 // B*L*H u32 (packed hi/lo)
  float* norm_all    = ws + (size_t)Bn*Ln*Hn;         // B*L
  float* read_ws     = norm_all + (size_t)Bn*Ln;      // B*H
  float* o1_ws       = read_ws + Bn*Hn;               // B*H
  uint32_t* wp       = (uint32_t*)(o1_ws + Bn*Hn);    // 81920 u32 packed weights

  p0_pack<<<dim3(160), dim3(256), 0, stream>>>(ff_w1, ff_w2, kp_w, wp);
  p1_fused<<<dim3(2048), dim3(256), 0, stream>>>(
      seq, embed_w, wp, ff_b1, ff_b2, ln_g, ln_b, knp_all, norm_all);
  p2_scan<<<dim3(64), dim3(512), 0, stream>>>(knp_all, norm_all, read_ws);
  p3a<<<dim3(64), dim3(128), 0, stream>>>(read_ws, rp_w, rp_b, o1_ws);
  p3b<<<dim3(125), dim3(256), 0, stream>>>(o1_ws, out_w, out_b, (float*)d_out);
}